// Round 1
// baseline (119.717 us; speedup 1.0000x reference)
//
#include <hip/hip_runtime.h>

// Problem shape (fixed by setup_inputs): B=8, Q=2048 -> N=16384 rows,
// D=1024, Dp=256, K=2048 prototypes.
#define N_ROWS 16384
#define DIM    1024
#define DP     256
#define NPROTO 2048

typedef float f32x4 __attribute__((ext_vector_type(4)));
typedef short s16x8 __attribute__((ext_vector_type(8)));
typedef short s16x4 __attribute__((ext_vector_type(4)));

__device__ __forceinline__ unsigned short f2bf(float f) {
  // round-to-nearest-even f32 -> bf16 (finite inputs only)
  unsigned int u = __builtin_bit_cast(unsigned int, f);
  u += 0x7FFFu + ((u >> 16) & 1u);
  return (unsigned short)(u >> 16);
}

// ---------------- prep 1: projT[j][d] = bf16(proj[d][j]) ----------------
__global__ void k_prep_projT(const float* __restrict__ proj,
                             unsigned short* __restrict__ projT) {
  int t = blockIdx.x * 256 + threadIdx.x;   // t = j*1024 + d, coalesced writes
  int j = t >> 10;
  int d = t & 1023;
  projT[t] = f2bf(proj[(size_t)d * DP + j]);
}

// ---------------- prep 2: Pb = bf16(P), pp[k] = sum(P[k]^2) -------------
__global__ void k_prep_proto(const float* __restrict__ P,
                             unsigned short* __restrict__ Pb,
                             float* __restrict__ pp) {
  int k = blockIdx.x;
  int d = threadIdx.x;                      // 256 threads = Dp
  float v = P[(size_t)k * DP + d];
  Pb[(size_t)k * DP + d] = f2bf(v);
  float s = v * v;
#pragma unroll
  for (int o = 1; o < 64; o <<= 1) s += __shfl_xor(s, o, 64);
  __shared__ float ws4[4];
  if ((threadIdx.x & 63) == 0) ws4[threadIdx.x >> 6] = s;
  __syncthreads();
  if (threadIdx.x == 0) pp[k] = ws4[0] + ws4[1] + ws4[2] + ws4[3];
}

// ------- GEMM1: Zb = normalize_rows((X - mean) @ proj), bf16 out --------
// BM=64, BN=256 (full Dp, so row-norm is in-block), BK=64. 4 waves, each
// owns a 64x64 column slice. 2-barrier single-buffered loop.
__global__ __launch_bounds__(256, 2)
void k_gemm1(const float* __restrict__ X, const float* __restrict__ mean,
             const unsigned short* __restrict__ projT,
             unsigned short* __restrict__ Zb) {
  constexpr int BM = 64, BK = 64, LD = BK + 8;  // +8 bf16 pad (16B) per row
  __shared__ __align__(16) unsigned short As[BM][LD];
  __shared__ __align__(16) unsigned short Bs[DP][LD];
  __shared__ float rowsq[4][BM];

  const int tid  = threadIdx.x;
  const int lane = tid & 63;
  const int wv   = tid >> 6;
  const int l15  = lane & 15;
  const int lhi  = lane >> 4;
  const int rb   = blockIdx.x * BM;

  f32x4 acc[4][4];
#pragma unroll
  for (int mf = 0; mf < 4; ++mf)
#pragma unroll
    for (int nf = 0; nf < 4; ++nf) acc[mf][nf] = (f32x4)0.0f;

  for (int kb = 0; kb < DIM; kb += BK) {
    // stage A: 64 rows x 64 d (fp32 -> centered bf16), 4 f32x4 per thread
#pragma unroll
    for (int i = 0; i < 4; ++i) {
      int ci  = i * 256 + tid;     // 1024 chunks of 4 floats
      int row = ci >> 4;
      int ch  = ci & 15;
      f32x4 x = *(const f32x4*)(X + (size_t)(rb + row) * DIM + kb + ch * 4);
      f32x4 m = *(const f32x4*)(mean + kb + ch * 4);
      s16x4 v;
      v[0] = (short)f2bf(x[0] - m[0]);
      v[1] = (short)f2bf(x[1] - m[1]);
      v[2] = (short)f2bf(x[2] - m[2]);
      v[3] = (short)f2bf(x[3] - m[3]);
      *(s16x4*)(&As[row][ch * 4]) = v;
    }
    // stage B: 256 rows (Dp) x 64 d from projT (bf16), 8 s16x8 per thread
#pragma unroll
    for (int i = 0; i < 8; ++i) {
      int ci  = i * 256 + tid;     // 2048 chunks of 8 bf16
      int row = ci >> 3;
      int ch  = ci & 7;
      *(s16x8*)(&Bs[row][ch * 8]) =
          *(const s16x8*)(projT + (size_t)row * DIM + kb + ch * 8);
    }
    __syncthreads();
#pragma unroll
    for (int kk = 0; kk < BK; kk += 32) {
      int k0 = kk + lhi * 8;
      s16x8 a[4], b[4];
#pragma unroll
      for (int mf = 0; mf < 4; ++mf)
        a[mf] = *(const s16x8*)(&As[mf * 16 + l15][k0]);
#pragma unroll
      for (int nf = 0; nf < 4; ++nf)
        b[nf] = *(const s16x8*)(&Bs[wv * 64 + nf * 16 + l15][k0]);
#pragma unroll
      for (int mf = 0; mf < 4; ++mf)
#pragma unroll
        for (int nf = 0; nf < 4; ++nf)
          acc[mf][nf] = __builtin_amdgcn_mfma_f32_16x16x32_bf16(
              a[mf], b[nf], acc[mf][nf], 0, 0, 0);
    }
    __syncthreads();
  }

  // epilogue: per-row sum of squares across this wave's 64 cols...
  float rs[4][4];
#pragma unroll
  for (int mf = 0; mf < 4; ++mf)
#pragma unroll
    for (int r = 0; r < 4; ++r) {
      float s = 0.0f;
#pragma unroll
      for (int nf = 0; nf < 4; ++nf) {
        float v = acc[mf][nf][r];
        s += v * v;
      }
      rs[mf][r] = s;
    }
  // ...reduce over the 16 lanes holding different cols of the same rows...
#pragma unroll
  for (int o = 1; o < 16; o <<= 1)
#pragma unroll
    for (int mf = 0; mf < 4; ++mf)
#pragma unroll
      for (int r = 0; r < 4; ++r)
        rs[mf][r] += __shfl_xor(rs[mf][r], o, 16);
  // ...then across the 4 waves via LDS.
  if (l15 == 0) {
#pragma unroll
    for (int mf = 0; mf < 4; ++mf)
#pragma unroll
      for (int r = 0; r < 4; ++r)
        rowsq[wv][mf * 16 + lhi * 4 + r] = rs[mf][r];
  }
  __syncthreads();
#pragma unroll
  for (int mf = 0; mf < 4; ++mf)
#pragma unroll
    for (int r = 0; r < 4; ++r) {
      int row  = mf * 16 + lhi * 4 + r;
      float n2 = rowsq[0][row] + rowsq[1][row] + rowsq[2][row] + rowsq[3][row];
      float inv = 1.0f / fmaxf(sqrtf(n2), 1e-12f);  // F.normalize eps
#pragma unroll
      for (int nf = 0; nf < 4; ++nf) {
        Zb[(size_t)(rb + row) * DP + wv * 64 + nf * 16 + l15] =
            f2bf(acc[mf][nf][r] * inv);
      }
    }
}

// -- GEMM2: out = -sqrt(max(1 + pp[k] - 2 * (Zb @ Pb^T), 0)), fp32 out ---
// BM=128, BN=128, BK=64; 4 waves as 2x2, each owns 64x64.
__global__ __launch_bounds__(256, 2)
void k_gemm2(const unsigned short* __restrict__ Zb,
             const unsigned short* __restrict__ Pb,
             const float* __restrict__ pp, float* __restrict__ out) {
  constexpr int BM = 128, BN = 128, BK = 64, LD = BK + 8;
  __shared__ __align__(16) unsigned short As[BM][LD];
  __shared__ __align__(16) unsigned short Bs[BN][LD];

  const int tid  = threadIdx.x;
  const int lane = tid & 63;
  const int wv   = tid >> 6;
  const int wm   = wv >> 1;
  const int wn   = wv & 1;
  const int l15  = lane & 15;
  const int lhi  = lane >> 4;
  const int rb   = blockIdx.x * BM;
  const int cb   = blockIdx.y * BN;

  f32x4 acc[4][4];
#pragma unroll
  for (int mf = 0; mf < 4; ++mf)
#pragma unroll
    for (int nf = 0; nf < 4; ++nf) acc[mf][nf] = (f32x4)0.0f;

  for (int kb = 0; kb < DP; kb += BK) {
#pragma unroll
    for (int i = 0; i < 4; ++i) {
      int ci  = i * 256 + tid;     // 1024 chunks of 8 bf16 (128 rows x 8)
      int row = ci >> 3;
      int ch  = ci & 7;
      *(s16x8*)(&As[row][ch * 8]) =
          *(const s16x8*)(Zb + (size_t)(rb + row) * DP + kb + ch * 8);
    }
#pragma unroll
    for (int i = 0; i < 4; ++i) {
      int ci  = i * 256 + tid;
      int row = ci >> 3;
      int ch  = ci & 7;
      *(s16x8*)(&Bs[row][ch * 8]) =
          *(const s16x8*)(Pb + (size_t)(cb + row) * DP + kb + ch * 8);
    }
    __syncthreads();
#pragma unroll
    for (int kk = 0; kk < BK; kk += 32) {
      int k0 = kk + lhi * 8;
      s16x8 a[4], b[4];
#pragma unroll
      for (int mf = 0; mf < 4; ++mf)
        a[mf] = *(const s16x8*)(&As[wm * 64 + mf * 16 + l15][k0]);
#pragma unroll
      for (int nf = 0; nf < 4; ++nf)
        b[nf] = *(const s16x8*)(&Bs[wn * 64 + nf * 16 + l15][k0]);
#pragma unroll
      for (int mf = 0; mf < 4; ++mf)
#pragma unroll
        for (int nf = 0; nf < 4; ++nf)
          acc[mf][nf] = __builtin_amdgcn_mfma_f32_16x16x32_bf16(
              a[mf], b[nf], acc[mf][nf], 0, 0, 0);
    }
    __syncthreads();
  }

  float ppv[4];
#pragma unroll
  for (int nf = 0; nf < 4; ++nf)
    ppv[nf] = pp[cb + wn * 64 + nf * 16 + l15];

#pragma unroll
  for (int mf = 0; mf < 4; ++mf)
#pragma unroll
    for (int r = 0; r < 4; ++r) {
      int row = rb + wm * 64 + mf * 16 + lhi * 4 + r;
#pragma unroll
      for (int nf = 0; nf < 4; ++nf) {
        int col  = cb + wn * 64 + nf * 16 + l15;
        float d2 = fmaxf(1.0f + ppv[nf] - 2.0f * acc[mf][nf][r], 0.0f);
        out[(size_t)row * NPROTO + col] = -sqrtf(d2);
      }
    }
}

extern "C" void kernel_launch(void* const* d_in, const int* in_sizes, int n_in,
                              void* d_out, int out_size, void* d_ws, size_t ws_size,
                              hipStream_t stream) {
  const float* X     = (const float*)d_in[0];  // [16384,1024]
  const float* mean  = (const float*)d_in[1];  // [1024]
  const float* proj  = (const float*)d_in[2];  // [1024,256]
  const float* proto = (const float*)d_in[3];  // [2048,256]
  float* out = (float*)d_out;                  // [16384,2048]

  char* ws = (char*)d_ws;
  // workspace layout (≈9.5 MB total)
  unsigned short* Zb    = (unsigned short*)(ws);                          // 8 MB
  unsigned short* projT = (unsigned short*)(ws + (size_t)8 * 1024 * 1024);// 512 KB
  unsigned short* Pb    = (unsigned short*)(ws + (size_t)8 * 1024 * 1024
                                               + 512 * 1024);             // 1 MB
  float* pp             = (float*)(ws + (size_t)8 * 1024 * 1024
                                      + 512 * 1024 + 1024 * 1024);        // 8 KB

  hipLaunchKernelGGL(k_prep_projT, dim3((DIM * DP) / 256), dim3(256), 0, stream,
                     proj, projT);
  hipLaunchKernelGGL(k_prep_proto, dim3(NPROTO), dim3(256), 0, stream,
                     proto, Pb, pp);
  hipLaunchKernelGGL(k_gemm1, dim3(N_ROWS / 64), dim3(256), 0, stream,
                     X, mean, projT, Zb);
  hipLaunchKernelGGL(k_gemm2, dim3(N_ROWS / 128, NPROTO / 128), dim3(256), 0,
                     stream, Zb, Pb, pp, out);
}

// Round 2
// 81.989 us; speedup vs baseline: 1.4602x; 1.4602x over previous
//
#include <hip/hip_runtime.h>

// Problem shape (fixed by setup_inputs): B=8, Q=2048 -> N=16384 rows,
// D=1024, Dp=256, K=2048 prototypes.
#define N_ROWS 16384
#define DIM    1024
#define DP     256
#define NPROTO 2048

typedef float f32x4 __attribute__((ext_vector_type(4)));
typedef short s16x8 __attribute__((ext_vector_type(8)));
typedef short s16x4 __attribute__((ext_vector_type(4)));

__device__ __forceinline__ unsigned short f2bf(float f) {
  // round-to-nearest-even f32 -> bf16 (finite inputs only)
  unsigned int u = __builtin_bit_cast(unsigned int, f);
  u += 0x7FFFu + ((u >> 16) & 1u);
  return (unsigned short)(u >> 16);
}

// ---------------- prep 1: projT[j][d] = bf16(proj[d][j]) ----------------
__global__ void k_prep_projT(const float* __restrict__ proj,
                             unsigned short* __restrict__ projT) {
  int t = blockIdx.x * 256 + threadIdx.x;   // t = j*1024 + d, coalesced writes
  int j = t >> 10;
  int d = t & 1023;
  projT[t] = f2bf(proj[(size_t)d * DP + j]);
}

// ---------------- prep 2: Pb = bf16(P), pp[k] = sum(P[k]^2) -------------
__global__ void k_prep_proto(const float* __restrict__ P,
                             unsigned short* __restrict__ Pb,
                             float* __restrict__ pp) {
  int k = blockIdx.x;
  int d = threadIdx.x;                      // 256 threads = Dp
  float v = P[(size_t)k * DP + d];
  Pb[(size_t)k * DP + d] = f2bf(v);
  float s = v * v;
#pragma unroll
  for (int o = 1; o < 64; o <<= 1) s += __shfl_xor(s, o, 64);
  __shared__ float ws4[4];
  if ((threadIdx.x & 63) == 0) ws4[threadIdx.x >> 6] = s;
  __syncthreads();
  if (threadIdx.x == 0) pp[k] = ws4[0] + ws4[1] + ws4[2] + ws4[3];
}

// ------- GEMM1: Zb = (X - mean) @ proj (UNNORMALIZED, bf16 out) ---------
// Also emits zzp[nb][row] = partial row sum-of-squares over this block's
// 128 columns (fp32, from the accumulators). Normalization is deferred to
// k_invn + gemm2 epilogue so the grid can be (512, 2) = 1024 blocks.
// BM=32, BN=128, BK=64. 4 waves side-by-side, each owns 32x32.
// 2-phase pipeline: dbuf LDS, reg-staged prefetch, ONE barrier per K-step.
__global__ __launch_bounds__(256, 3)
void k_gemm1(const float* __restrict__ X, const float* __restrict__ mean,
             const unsigned short* __restrict__ projT,
             unsigned short* __restrict__ Zb, float* __restrict__ zzp) {
  constexpr int BM = 32, BN = 128, BK = 64, LD = BK + 8;  // +8 bf16 pad
  __shared__ __align__(16) unsigned short As[2][BM][LD];  // 9216 B
  __shared__ __align__(16) unsigned short Bs[2][BN][LD];  // 36864 B
  __shared__ float rowsq[4][BM];                          // 512 B

  const int tid  = threadIdx.x;
  const int lane = tid & 63;
  const int wn   = tid >> 6;        // wave column block (0..3)
  const int l15  = lane & 15;
  const int lhi  = lane >> 4;
  const int rb   = blockIdx.x * BM; // 512 row tiles
  const int nb   = blockIdx.y;      // 2 column halves
  const int cb   = nb * BN;

  // Staging decomposition (per thread):
  //  A: 32 rows x 64 f32 = 512 f32x4 chunks -> 2/thread.
  //     chunk ci = i*256+tid: row = i*16 + (tid>>4), ch = tid&15 (both i share ch)
  //  B: 128 rows x 64 bf16 = 1024 s16x8 chunks -> 4/thread.
  //     chunk ci = i*256+tid: row = i*32 + (tid>>3), ch = tid&7
  const int arow = tid >> 4;
  const int ach4 = (tid & 15) * 4;
  const int brow = tid >> 3;
  const int bch8 = (tid & 7) * 8;
  const float* xbase = X + (size_t)(rb + arow) * DIM + ach4;
  const float* mbase = mean + ach4;
  const unsigned short* bbase = projT + (size_t)(cb + brow) * DIM + bch8;

  f32x4 acc[2][2];
#pragma unroll
  for (int mf = 0; mf < 2; ++mf)
#pragma unroll
    for (int nf = 0; nf < 2; ++nf) acc[mf][nf] = (f32x4)0.0f;

  f32x4 xr0, xr1, mr;
  s16x8 br0, br1, br2, br3;

#define G1_ISSUE(KB)                                                         \
  {                                                                          \
    xr0 = *(const f32x4*)(xbase + (KB));                                     \
    xr1 = *(const f32x4*)(xbase + 16 * DIM + (KB));                          \
    mr  = *(const f32x4*)(mbase + (KB));                                     \
    br0 = *(const s16x8*)(bbase + (KB));                                     \
    br1 = *(const s16x8*)(bbase + (size_t)32 * DIM + (KB));                  \
    br2 = *(const s16x8*)(bbase + (size_t)64 * DIM + (KB));                  \
    br3 = *(const s16x8*)(bbase + (size_t)96 * DIM + (KB));                  \
  }

#define G1_WRITE(CUR)                                                        \
  {                                                                          \
    f32x4 c0 = xr0 - mr;                                                     \
    f32x4 c1 = xr1 - mr;                                                     \
    s16x4 v0, v1;                                                            \
    v0[0] = (short)f2bf(c0[0]); v0[1] = (short)f2bf(c0[1]);                  \
    v0[2] = (short)f2bf(c0[2]); v0[3] = (short)f2bf(c0[3]);                  \
    v1[0] = (short)f2bf(c1[0]); v1[1] = (short)f2bf(c1[1]);                  \
    v1[2] = (short)f2bf(c1[2]); v1[3] = (short)f2bf(c1[3]);                  \
    *(s16x4*)(&As[CUR][arow][ach4])      = v0;                               \
    *(s16x4*)(&As[CUR][arow + 16][ach4]) = v1;                               \
    *(s16x8*)(&Bs[CUR][brow][bch8])      = br0;                              \
    *(s16x8*)(&Bs[CUR][brow + 32][bch8]) = br1;                              \
    *(s16x8*)(&Bs[CUR][brow + 64][bch8]) = br2;                              \
    *(s16x8*)(&Bs[CUR][brow + 96][bch8]) = br3;                              \
  }

#define G1_COMPUTE(CUR)                                                      \
  {                                                                          \
    _Pragma("unroll")                                                        \
    for (int kk = 0; kk < BK; kk += 32) {                                    \
      int k0 = kk + lhi * 8;                                                 \
      s16x8 a[2], b[2];                                                      \
      _Pragma("unroll")                                                      \
      for (int mf = 0; mf < 2; ++mf)                                         \
        a[mf] = *(const s16x8*)(&As[CUR][mf * 16 + l15][k0]);                \
      _Pragma("unroll")                                                      \
      for (int nf = 0; nf < 2; ++nf)                                         \
        b[nf] = *(const s16x8*)(&Bs[CUR][wn * 32 + nf * 16 + l15][k0]);      \
      _Pragma("unroll")                                                      \
      for (int mf = 0; mf < 2; ++mf)                                         \
        _Pragma("unroll")                                                    \
        for (int nf = 0; nf < 2; ++nf)                                       \
          acc[mf][nf] = __builtin_amdgcn_mfma_f32_16x16x32_bf16(             \
              a[mf], b[nf], acc[mf][nf], 0, 0, 0);                           \
    }                                                                        \
  }

  G1_ISSUE(0);
#pragma unroll 2
  for (int t = 0; t < DIM / BK; ++t) {
    const int cur = t & 1;
    G1_WRITE(cur);                      // waits on this step's loads
    if (t < DIM / BK - 1) G1_ISSUE((t + 1) * BK);  // next tile in flight
    __syncthreads();                    // single barrier per step (dbuf)
    G1_COMPUTE(cur);
  }

  // ---- epilogue: partial row sum-of-squares over this block's 128 cols ----
#pragma unroll
  for (int mf = 0; mf < 2; ++mf)
#pragma unroll
    for (int r = 0; r < 4; ++r) {
      float s = acc[mf][0][r] * acc[mf][0][r] + acc[mf][1][r] * acc[mf][1][r];
#pragma unroll
      for (int o = 1; o < 16; o <<= 1) s += __shfl_xor(s, o, 16);
      if (l15 == 0) rowsq[wn][mf * 16 + lhi * 4 + r] = s;
    }
  __syncthreads();
  if (tid < BM) {
    float zz = rowsq[0][tid] + rowsq[1][tid] + rowsq[2][tid] + rowsq[3][tid];
    zzp[(size_t)nb * N_ROWS + rb + tid] = zz;
  }
  // ---- write unnormalized centered Z in bf16 ----
#pragma unroll
  for (int mf = 0; mf < 2; ++mf)
#pragma unroll
    for (int r = 0; r < 4; ++r) {
      int row = rb + mf * 16 + lhi * 4 + r;
#pragma unroll
      for (int nf = 0; nf < 2; ++nf) {
        int col = cb + wn * 32 + nf * 16 + l15;
        Zb[(size_t)row * DP + col] = f2bf(acc[mf][nf][r]);
      }
    }
#undef G1_ISSUE
#undef G1_WRITE
#undef G1_COMPUTE
}

// ---------------- invn[row] = 1 / max(||z_row||, eps) -------------------
__global__ void k_invn(const float* __restrict__ zzp,
                       float* __restrict__ invn) {
  int r = blockIdx.x * 256 + threadIdx.x;
  float zz = zzp[r] + zzp[N_ROWS + r];
  invn[r] = 1.0f / fmaxf(sqrtf(zz), 1e-12f);  // F.normalize eps
}

// GEMM2: out = -sqrt(max(1 + pp[k] - 2 * (Zb @ Pb^T) * invn[row], 0))
// BM=128, BN=128, BK=64; 4 waves as 2x2, each owns 64x64.
__global__ __launch_bounds__(256, 2)
void k_gemm2(const unsigned short* __restrict__ Zb,
             const unsigned short* __restrict__ Pb,
             const float* __restrict__ pp, const float* __restrict__ invn,
             float* __restrict__ out) {
  constexpr int BM = 128, BN = 128, BK = 64, LD = BK + 8;
  __shared__ __align__(16) unsigned short As[BM][LD];
  __shared__ __align__(16) unsigned short Bs[BN][LD];

  const int tid  = threadIdx.x;
  const int lane = tid & 63;
  const int wv   = tid >> 6;
  const int wm   = wv >> 1;
  const int wn   = wv & 1;
  const int l15  = lane & 15;
  const int lhi  = lane >> 4;
  const int rb   = blockIdx.x * BM;
  const int cb   = blockIdx.y * BN;

  f32x4 acc[4][4];
#pragma unroll
  for (int mf = 0; mf < 4; ++mf)
#pragma unroll
    for (int nf = 0; nf < 4; ++nf) acc[mf][nf] = (f32x4)0.0f;

  for (int kb = 0; kb < DP; kb += BK) {
#pragma unroll
    for (int i = 0; i < 4; ++i) {
      int ci  = i * 256 + tid;     // 1024 chunks of 8 bf16 (128 rows x 8)
      int row = ci >> 3;
      int ch  = ci & 7;
      *(s16x8*)(&As[row][ch * 8]) =
          *(const s16x8*)(Zb + (size_t)(rb + row) * DP + kb + ch * 8);
    }
#pragma unroll
    for (int i = 0; i < 4; ++i) {
      int ci  = i * 256 + tid;
      int row = ci >> 3;
      int ch  = ci & 7;
      *(s16x8*)(&Bs[row][ch * 8]) =
          *(const s16x8*)(Pb + (size_t)(cb + row) * DP + kb + ch * 8);
    }
    __syncthreads();
#pragma unroll
    for (int kk = 0; kk < BK; kk += 32) {
      int k0 = kk + lhi * 8;
      s16x8 a[4], b[4];
#pragma unroll
      for (int mf = 0; mf < 4; ++mf)
        a[mf] = *(const s16x8*)(&As[wm * 64 + mf * 16 + l15][k0]);
#pragma unroll
      for (int nf = 0; nf < 4; ++nf)
        b[nf] = *(const s16x8*)(&Bs[wn * 64 + nf * 16 + l15][k0]);
#pragma unroll
      for (int mf = 0; mf < 4; ++mf)
#pragma unroll
        for (int nf = 0; nf < 4; ++nf)
          acc[mf][nf] = __builtin_amdgcn_mfma_f32_16x16x32_bf16(
              a[mf], b[nf], acc[mf][nf], 0, 0, 0);
    }
    __syncthreads();
  }

  float ppv[4];
#pragma unroll
  for (int nf = 0; nf < 4; ++nf)
    ppv[nf] = pp[cb + wn * 64 + nf * 16 + l15];

#pragma unroll
  for (int mf = 0; mf < 4; ++mf)
#pragma unroll
    for (int r = 0; r < 4; ++r) {
      int row   = rb + wm * 64 + mf * 16 + lhi * 4 + r;
      float inv = invn[row];
#pragma unroll
      for (int nf = 0; nf < 4; ++nf) {
        int col  = cb + wn * 64 + nf * 16 + l15;
        float d2 = fmaxf(1.0f + ppv[nf] - 2.0f * acc[mf][nf][r] * inv, 0.0f);
        out[(size_t)row * NPROTO + col] = -sqrtf(d2);
      }
    }
}

extern "C" void kernel_launch(void* const* d_in, const int* in_sizes, int n_in,
                              void* d_out, int out_size, void* d_ws, size_t ws_size,
                              hipStream_t stream) {
  const float* X     = (const float*)d_in[0];  // [16384,1024]
  const float* mean  = (const float*)d_in[1];  // [1024]
  const float* proj  = (const float*)d_in[2];  // [1024,256]
  const float* proto = (const float*)d_in[3];  // [2048,256]
  float* out = (float*)d_out;                  // [16384,2048]

  char* ws = (char*)d_ws;
  // workspace layout (~9.7 MB total)
  size_t off = 0;
  unsigned short* Zb    = (unsigned short*)(ws + off); off += (size_t)N_ROWS * DP * 2;   // 8 MB
  unsigned short* projT = (unsigned short*)(ws + off); off += (size_t)DIM * DP * 2;      // 512 KB
  unsigned short* Pb    = (unsigned short*)(ws + off); off += (size_t)NPROTO * DP * 2;   // 1 MB
  float* pp             = (float*)(ws + off);          off += (size_t)NPROTO * 4;        // 8 KB
  float* zzp            = (float*)(ws + off);          off += (size_t)2 * N_ROWS * 4;    // 128 KB
  float* invn           = (float*)(ws + off);          off += (size_t)N_ROWS * 4;        // 64 KB

  hipLaunchKernelGGL(k_prep_projT, dim3((DIM * DP) / 256), dim3(256), 0, stream,
                     proj, projT);
  hipLaunchKernelGGL(k_prep_proto, dim3(NPROTO), dim3(256), 0, stream,
                     proto, Pb, pp);
  hipLaunchKernelGGL(k_gemm1, dim3(N_ROWS / 32, 2), dim3(256), 0, stream,
                     X, mean, projT, Zb, zzp);
  hipLaunchKernelGGL(k_invn, dim3(N_ROWS / 256), dim3(256), 0, stream,
                     zzp, invn);
  hipLaunchKernelGGL(k_gemm2, dim3(N_ROWS / 128, NPROTO / 128), dim3(256), 0,
                     stream, Zb, Pb, pp, invn, out);
}

// Round 3
// 81.543 us; speedup vs baseline: 1.4681x; 1.0055x over previous
//
#include <hip/hip_runtime.h>

// Problem shape (fixed by setup_inputs): B=8, Q=2048 -> N=16384 rows,
// D=1024, Dp=256, K=2048 prototypes.
#define N_ROWS 16384
#define DIM    1024
#define DP     256
#define NPROTO 2048

typedef float f32x4 __attribute__((ext_vector_type(4)));
typedef short s16x8 __attribute__((ext_vector_type(8)));
typedef short s16x4 __attribute__((ext_vector_type(4)));

__device__ __forceinline__ unsigned short f2bf(float f) {
  // round-to-nearest-even f32 -> bf16 (finite inputs only)
  unsigned int u = __builtin_bit_cast(unsigned int, f);
  u += 0x7FFFu + ((u >> 16) & 1u);
  return (unsigned short)(u >> 16);
}

// ---- fused prep: projT[j][d]=bf16(proj[d][j]); Pb=bf16(P); pp=rowsum(P^2) ----
__global__ void k_prep(const float* __restrict__ proj,
                       const float* __restrict__ P,
                       unsigned short* __restrict__ projT,
                       unsigned short* __restrict__ Pb,
                       float* __restrict__ pp) {
  int b = blockIdx.x;
  if (b < (DIM * DP) / 256) {
    int t = b * 256 + threadIdx.x;          // t = j*1024 + d, coalesced writes
    int j = t >> 10;
    int d = t & 1023;
    projT[t] = f2bf(proj[(size_t)d * DP + j]);
  } else {
    int k = b - (DIM * DP) / 256;
    int d = threadIdx.x;                    // 256 threads = Dp
    float v = P[(size_t)k * DP + d];
    Pb[(size_t)k * DP + d] = f2bf(v);
    float s = v * v;
#pragma unroll
    for (int o = 1; o < 64; o <<= 1) s += __shfl_xor(s, o, 64);
    __shared__ float ws4[4];
    if ((threadIdx.x & 63) == 0) ws4[threadIdx.x >> 6] = s;
    __syncthreads();
    if (threadIdx.x == 0) pp[k] = ws4[0] + ws4[1] + ws4[2] + ws4[3];
  }
}

// ------- GEMM1: Zb = (X - mean) @ proj (UNNORMALIZED, bf16 out) ---------
// Also emits zzp[nb][row] = partial row sum-of-squares over this block's
// 128 columns. Normalization is applied in gemm2's epilogue.
// BM=32, BN=128, BK=64. 4 waves side-by-side, each owns 32x32.
// 2-phase pipeline: dbuf LDS, reg-staged prefetch, ONE barrier per K-step.
__global__ __launch_bounds__(256, 3)
void k_gemm1(const float* __restrict__ X, const float* __restrict__ mean,
             const unsigned short* __restrict__ projT,
             unsigned short* __restrict__ Zb, float* __restrict__ zzp) {
  constexpr int BM = 32, BN = 128, BK = 64, LD = BK + 8;  // +8 bf16 pad
  __shared__ __align__(16) unsigned short As[2][BM][LD];  // 9216 B
  __shared__ __align__(16) unsigned short Bs[2][BN][LD];  // 36864 B
  __shared__ float rowsq[4][BM];                          // 512 B

  const int tid  = threadIdx.x;
  const int lane = tid & 63;
  const int wn   = tid >> 6;        // wave column block (0..3)
  const int l15  = lane & 15;
  const int lhi  = lane >> 4;
  const int rb   = blockIdx.x * BM; // 512 row tiles
  const int nb   = blockIdx.y;      // 2 column halves
  const int cb   = nb * BN;

  const int arow = tid >> 4;
  const int ach4 = (tid & 15) * 4;
  const int brow = tid >> 3;
  const int bch8 = (tid & 7) * 8;
  const float* xbase = X + (size_t)(rb + arow) * DIM + ach4;
  const float* mbase = mean + ach4;
  const unsigned short* bbase = projT + (size_t)(cb + brow) * DIM + bch8;

  f32x4 acc[2][2];
#pragma unroll
  for (int mf = 0; mf < 2; ++mf)
#pragma unroll
    for (int nf = 0; nf < 2; ++nf) acc[mf][nf] = (f32x4)0.0f;

  f32x4 xr0, xr1, mr;
  s16x8 br0, br1, br2, br3;

#define G1_ISSUE(KB)                                                         \
  {                                                                          \
    xr0 = *(const f32x4*)(xbase + (KB));                                     \
    xr1 = *(const f32x4*)(xbase + 16 * DIM + (KB));                          \
    mr  = *(const f32x4*)(mbase + (KB));                                     \
    br0 = *(const s16x8*)(bbase + (KB));                                     \
    br1 = *(const s16x8*)(bbase + (size_t)32 * DIM + (KB));                  \
    br2 = *(const s16x8*)(bbase + (size_t)64 * DIM + (KB));                  \
    br3 = *(const s16x8*)(bbase + (size_t)96 * DIM + (KB));                  \
  }

#define G1_WRITE(CUR)                                                        \
  {                                                                          \
    f32x4 c0 = xr0 - mr;                                                     \
    f32x4 c1 = xr1 - mr;                                                     \
    s16x4 v0, v1;                                                            \
    v0[0] = (short)f2bf(c0[0]); v0[1] = (short)f2bf(c0[1]);                  \
    v0[2] = (short)f2bf(c0[2]); v0[3] = (short)f2bf(c0[3]);                  \
    v1[0] = (short)f2bf(c1[0]); v1[1] = (short)f2bf(c1[1]);                  \
    v1[2] = (short)f2bf(c1[2]); v1[3] = (short)f2bf(c1[3]);                  \
    *(s16x4*)(&As[CUR][arow][ach4])      = v0;                               \
    *(s16x4*)(&As[CUR][arow + 16][ach4]) = v1;                               \
    *(s16x8*)(&Bs[CUR][brow][bch8])      = br0;                              \
    *(s16x8*)(&Bs[CUR][brow + 32][bch8]) = br1;                              \
    *(s16x8*)(&Bs[CUR][brow + 64][bch8]) = br2;                              \
    *(s16x8*)(&Bs[CUR][brow + 96][bch8]) = br3;                              \
  }

#define G1_COMPUTE(CUR)                                                      \
  {                                                                          \
    _Pragma("unroll")                                                        \
    for (int kk = 0; kk < BK; kk += 32) {                                    \
      int k0 = kk + lhi * 8;                                                 \
      s16x8 a[2], b[2];                                                      \
      _Pragma("unroll")                                                      \
      for (int mf = 0; mf < 2; ++mf)                                         \
        a[mf] = *(const s16x8*)(&As[CUR][mf * 16 + l15][k0]);                \
      _Pragma("unroll")                                                      \
      for (int nf = 0; nf < 2; ++nf)                                         \
        b[nf] = *(const s16x8*)(&Bs[CUR][wn * 32 + nf * 16 + l15][k0]);      \
      _Pragma("unroll")                                                      \
      for (int mf = 0; mf < 2; ++mf)                                         \
        _Pragma("unroll")                                                    \
        for (int nf = 0; nf < 2; ++nf)                                       \
          acc[mf][nf] = __builtin_amdgcn_mfma_f32_16x16x32_bf16(             \
              a[mf], b[nf], acc[mf][nf], 0, 0, 0);                           \
    }                                                                        \
  }

  G1_ISSUE(0);
#pragma unroll 2
  for (int t = 0; t < DIM / BK; ++t) {
    const int cur = t & 1;
    G1_WRITE(cur);                      // waits on this step's loads
    if (t < DIM / BK - 1) G1_ISSUE((t + 1) * BK);  // next tile in flight
    __syncthreads();                    // single barrier per step (dbuf)
    G1_COMPUTE(cur);
  }

  // ---- epilogue: partial row sum-of-squares over this block's 128 cols ----
#pragma unroll
  for (int mf = 0; mf < 2; ++mf)
#pragma unroll
    for (int r = 0; r < 4; ++r) {
      float s = acc[mf][0][r] * acc[mf][0][r] + acc[mf][1][r] * acc[mf][1][r];
#pragma unroll
      for (int o = 1; o < 16; o <<= 1) s += __shfl_xor(s, o, 16);
      if (l15 == 0) rowsq[wn][mf * 16 + lhi * 4 + r] = s;
    }
  __syncthreads();
  if (tid < BM) {
    float zz = rowsq[0][tid] + rowsq[1][tid] + rowsq[2][tid] + rowsq[3][tid];
    zzp[(size_t)nb * N_ROWS + rb + tid] = zz;
  }
  // ---- write unnormalized centered Z in bf16 ----
#pragma unroll
  for (int mf = 0; mf < 2; ++mf)
#pragma unroll
    for (int r = 0; r < 4; ++r) {
      int row = rb + mf * 16 + lhi * 4 + r;
#pragma unroll
      for (int nf = 0; nf < 2; ++nf) {
        int col = cb + wn * 32 + nf * 16 + l15;
        Zb[(size_t)row * DP + col] = f2bf(acc[mf][nf][r]);
      }
    }
#undef G1_ISSUE
#undef G1_WRITE
#undef G1_COMPUTE
}

// GEMM2: out = -sqrt(max(1 + pp[k] - 2 * (Zb @ Pb^T) * invn[row], 0))
// BM=128, BN=128, BK=64; 4 waves as 2x2, each owns 64x64.
// 2-phase reg-staged dbuf pipeline; invn computed in-kernel from zzp;
// XCD-aware block swizzle (each XCD: 16x16 tile region -> 2 MB L2 set).
__global__ __launch_bounds__(256, 2)
void k_gemm2(const unsigned short* __restrict__ Zb,
             const unsigned short* __restrict__ Pb,
             const float* __restrict__ pp, const float* __restrict__ zzp,
             float* __restrict__ out) {
  constexpr int BM = 128, BN = 128, BK = 64, LD = BK + 8;
  __shared__ __align__(16) unsigned short As[2][BM][LD];  // 36864 B
  __shared__ __align__(16) unsigned short Bs[2][BN][LD];  // 36864 B
  __shared__ float invs[BM];

  const int tid  = threadIdx.x;
  const int lane = tid & 63;
  const int wv   = tid >> 6;
  const int wm   = wv >> 1;
  const int wn   = wv & 1;
  const int l15  = lane & 15;
  const int lhi  = lane >> 4;

  // XCD swizzle: 2048 blocks; xcd = bid%8 gets a contiguous 16(row)x16(col)
  // tile region -> per-XCD working set = 1MB Zb + 1MB Pb (L2-resident).
  const int bid = blockIdx.x;
  const int xcd = bid & 7;
  const int loc = bid >> 3;                 // [0,256)
  const int bx  = xcd * 16 + (loc & 15);    // row tile [0,128)
  const int by  = loc >> 4;                 // col tile [0,16)
  const int rb  = bx * BM;
  const int cb  = by * BN;

  // staging: 128 rows x 64 bf16 per matrix per tile = 4 s16x8 per thread
  const int srow = tid >> 3;                // [0,32), step 32 per chunk
  const int sch8 = (tid & 7) * 8;
  const unsigned short* abase = Zb + (size_t)(rb + srow) * DP + sch8;
  const unsigned short* bbase = Pb + (size_t)(cb + srow) * DP + sch8;

  f32x4 acc[4][4];
#pragma unroll
  for (int mf = 0; mf < 4; ++mf)
#pragma unroll
    for (int nf = 0; nf < 4; ++nf) acc[mf][nf] = (f32x4)0.0f;

  s16x8 ar[4], br[4];

#define G2_ISSUE(KB)                                                         \
  {                                                                          \
    _Pragma("unroll")                                                        \
    for (int i = 0; i < 4; ++i) {                                            \
      ar[i] = *(const s16x8*)(abase + (size_t)i * 32 * DP + (KB));           \
      br[i] = *(const s16x8*)(bbase + (size_t)i * 32 * DP + (KB));           \
    }                                                                        \
  }

#define G2_WRITE(CUR)                                                       \
  {                                                                          \
    _Pragma("unroll")                                                        \
    for (int i = 0; i < 4; ++i) {                                            \
      *(s16x8*)(&As[CUR][srow + i * 32][sch8]) = ar[i];                      \
      *(s16x8*)(&Bs[CUR][srow + i * 32][sch8]) = br[i];                      \
    }                                                                        \
  }

#define G2_COMPUTE(CUR)                                                      \
  {                                                                          \
    _Pragma("unroll")                                                        \
    for (int kk = 0; kk < BK; kk += 32) {                                    \
      int k0 = kk + lhi * 8;                                                 \
      s16x8 a[4], b[4];                                                      \
      _Pragma("unroll")                                                      \
      for (int mf = 0; mf < 4; ++mf)                                         \
        a[mf] = *(const s16x8*)(&As[CUR][wm * 64 + mf * 16 + l15][k0]);      \
      _Pragma("unroll")                                                      \
      for (int nf = 0; nf < 4; ++nf)                                         \
        b[nf] = *(const s16x8*)(&Bs[CUR][wn * 64 + nf * 16 + l15][k0]);      \
      _Pragma("unroll")                                                      \
      for (int mf = 0; mf < 4; ++mf)                                         \
        _Pragma("unroll")                                                    \
        for (int nf = 0; nf < 4; ++nf)                                       \
          acc[mf][nf] = __builtin_amdgcn_mfma_f32_16x16x32_bf16(             \
              a[mf], b[nf], acc[mf][nf], 0, 0, 0);                           \
    }                                                                        \
  }

  G2_ISSUE(0);
#pragma unroll 2
  for (int t = 0; t < DP / BK; ++t) {
    const int cur = t & 1;
    G2_WRITE(cur);
    if (t < DP / BK - 1) G2_ISSUE((t + 1) * BK);
    __syncthreads();
    G2_COMPUTE(cur);
  }

  // per-row inverse norm for this block's 128 rows (from gemm1 partials)
  if (tid < BM) {
    float zz = zzp[rb + tid] + zzp[N_ROWS + rb + tid];
    invs[tid] = 1.0f / fmaxf(sqrtf(zz), 1e-12f);  // F.normalize eps
  }
  __syncthreads();

  float ppv[4];
#pragma unroll
  for (int nf = 0; nf < 4; ++nf)
    ppv[nf] = pp[cb + wn * 64 + nf * 16 + l15];

#pragma unroll
  for (int mf = 0; mf < 4; ++mf)
#pragma unroll
    for (int r = 0; r < 4; ++r) {
      int lrow  = wm * 64 + mf * 16 + lhi * 4 + r;
      float inv = invs[lrow];
      int row   = rb + lrow;
#pragma unroll
      for (int nf = 0; nf < 4; ++nf) {
        int col  = cb + wn * 64 + nf * 16 + l15;
        float d2 = fmaxf(1.0f + ppv[nf] - 2.0f * acc[mf][nf][r] * inv, 0.0f);
        out[(size_t)row * NPROTO + col] = -sqrtf(d2);
      }
    }
#undef G2_ISSUE
#undef G2_WRITE
#undef G2_COMPUTE
}

extern "C" void kernel_launch(void* const* d_in, const int* in_sizes, int n_in,
                              void* d_out, int out_size, void* d_ws, size_t ws_size,
                              hipStream_t stream) {
  const float* X     = (const float*)d_in[0];  // [16384,1024]
  const float* mean  = (const float*)d_in[1];  // [1024]
  const float* proj  = (const float*)d_in[2];  // [1024,256]
  const float* proto = (const float*)d_in[3];  // [2048,256]
  float* out = (float*)d_out;                  // [16384,2048]

  char* ws = (char*)d_ws;
  // workspace layout (~9.7 MB total)
  size_t off = 0;
  unsigned short* Zb    = (unsigned short*)(ws + off); off += (size_t)N_ROWS * DP * 2;   // 8 MB
  unsigned short* projT = (unsigned short*)(ws + off); off += (size_t)DIM * DP * 2;      // 512 KB
  unsigned short* Pb    = (unsigned short*)(ws + off); off += (size_t)NPROTO * DP * 2;   // 1 MB
  float* pp             = (float*)(ws + off);          off += (size_t)NPROTO * 4;        // 8 KB
  float* zzp            = (float*)(ws + off);          off += (size_t)2 * N_ROWS * 4;    // 128 KB

  hipLaunchKernelGGL(k_prep, dim3((DIM * DP) / 256 + NPROTO), dim3(256), 0,
                     stream, proj, proto, projT, Pb, pp);
  hipLaunchKernelGGL(k_gemm1, dim3(N_ROWS / 32, 2), dim3(256), 0, stream,
                     X, mean, projT, Zb, zzp);
  hipLaunchKernelGGL(k_gemm2, dim3((N_ROWS / 128) * (NPROTO / 128)), dim3(256),
                     0, stream, Zb, Pb, pp, zzp, out);
}

// Round 4
// 79.171 us; speedup vs baseline: 1.5121x; 1.0300x over previous
//
#include <hip/hip_runtime.h>

// Problem shape (fixed by setup_inputs): B=8, Q=2048 -> N=16384 rows,
// D=1024, Dp=256, K=2048 prototypes.
#define N_ROWS 16384
#define DIM    1024
#define DP     256
#define NPROTO 2048

typedef float f32x4 __attribute__((ext_vector_type(4)));
typedef short s16x8 __attribute__((ext_vector_type(8)));
typedef short s16x4 __attribute__((ext_vector_type(4)));

__device__ __forceinline__ unsigned short f2bf(float f) {
  // round-to-nearest-even f32 -> bf16 (finite inputs only)
  unsigned int u = __builtin_bit_cast(unsigned int, f);
  u += 0x7FFFu + ((u >> 16) & 1u);
  return (unsigned short)(u >> 16);
}

// ---- fused prep: projT[j][d]=bf16(proj[d][j]); Pb=bf16(P); pp=rowsum(P^2) ----
__global__ void k_prep(const float* __restrict__ proj,
                       const float* __restrict__ P,
                       unsigned short* __restrict__ projT,
                       unsigned short* __restrict__ Pb,
                       float* __restrict__ pp) {
  int b = blockIdx.x;
  if (b < (DIM * DP) / 256) {
    int t = b * 256 + threadIdx.x;          // t = j*1024 + d, coalesced writes
    int j = t >> 10;
    int d = t & 1023;
    projT[t] = f2bf(proj[(size_t)d * DP + j]);
  } else {
    int k = b - (DIM * DP) / 256;
    int d = threadIdx.x;                    // 256 threads = Dp
    float v = P[(size_t)k * DP + d];
    Pb[(size_t)k * DP + d] = f2bf(v);
    float s = v * v;
#pragma unroll
    for (int o = 1; o < 64; o <<= 1) s += __shfl_xor(s, o, 64);
    __shared__ float ws4[4];
    if ((threadIdx.x & 63) == 0) ws4[threadIdx.x >> 6] = s;
    __syncthreads();
    if (threadIdx.x == 0) pp[k] = ws4[0] + ws4[1] + ws4[2] + ws4[3];
  }
}

// ---- GEMM1: Zb = normalize_rows((X - mean) @ proj), bf16 out ----
// BM=32, BN=256 (FULL Dp -> X read exactly once, norm stays in-block),
// BK=32 -> 32 K-steps of small loads. 512 threads = 8 waves side-by-side,
// each wave owns a 32x32 column slice. 2-phase reg-staged dbuf pipeline,
// one barrier per K-step. Grid = 512 blocks -> 2 blocks/CU (LDS 47 KB).
__global__ __launch_bounds__(512, 4)
void k_gemm1(const float* __restrict__ X, const float* __restrict__ mean,
             const unsigned short* __restrict__ projT,
             unsigned short* __restrict__ Zb) {
  constexpr int BM = 32, BN = 256, BK = 32, LD = BK + 8;  // +8 bf16 pad
  __shared__ __align__(16) unsigned short As[2][BM][LD];  //  5120 B
  __shared__ __align__(16) unsigned short Bs[2][BN][LD];  // 40960 B
  __shared__ float rowsq[8][BM];                          //  1024 B

  const int tid  = threadIdx.x;
  const int lane = tid & 63;
  const int wn   = tid >> 6;        // wave column block (0..7)
  const int l15  = lane & 15;
  const int lhi  = lane >> 4;
  const int rb   = blockIdx.x * BM; // 512 row tiles

  // staging decomposition:
  //  A: 32 rows x 32 f32 = 256 f32x4 chunks -> threads 0..255, 1 each
  //  B: 256 rows x 32 bf16 = 1024 s16x8 chunks -> 512 threads, 2 each
  const int arow = tid >> 3;             // valid for tid<256
  const int ach4 = (tid & 7) * 4;
  const int brow = tid >> 2;             // [0,128), second chunk +128
  const int bch8 = (tid & 3) * 8;
  const float* xbase = X + (size_t)(rb + arow) * DIM + ach4;
  const float* mbase = mean + ach4;
  const unsigned short* bbase = projT + (size_t)brow * DIM + bch8;

  f32x4 acc[2][2];
#pragma unroll
  for (int mf = 0; mf < 2; ++mf)
#pragma unroll
    for (int nf = 0; nf < 2; ++nf) acc[mf][nf] = (f32x4)0.0f;

  f32x4 xr0, mr;
  s16x8 br0, br1;

#define G1_ISSUE(KB)                                                         \
  {                                                                          \
    if (tid < 256) {                                                         \
      xr0 = *(const f32x4*)(xbase + (KB));                                   \
      mr  = *(const f32x4*)(mbase + (KB));                                   \
    }                                                                        \
    br0 = *(const s16x8*)(bbase + (KB));                                     \
    br1 = *(const s16x8*)(bbase + (size_t)128 * DIM + (KB));                 \
  }

#define G1_WRITE(CUR)                                                        \
  {                                                                          \
    if (tid < 256) {                                                         \
      f32x4 c0 = xr0 - mr;                                                   \
      s16x4 v0;                                                              \
      v0[0] = (short)f2bf(c0[0]); v0[1] = (short)f2bf(c0[1]);                \
      v0[2] = (short)f2bf(c0[2]); v0[3] = (short)f2bf(c0[3]);                \
      *(s16x4*)(&As[CUR][arow][ach4]) = v0;                                  \
    }                                                                        \
    *(s16x8*)(&Bs[CUR][brow][bch8])       = br0;                             \
    *(s16x8*)(&Bs[CUR][brow + 128][bch8]) = br1;                             \
  }

#define G1_COMPUTE(CUR)                                                      \
  {                                                                          \
    int k0 = lhi * 8;                                                        \
    s16x8 a[2], b[2];                                                        \
    _Pragma("unroll")                                                        \
    for (int mf = 0; mf < 2; ++mf)                                           \
      a[mf] = *(const s16x8*)(&As[CUR][mf * 16 + l15][k0]);                  \
    _Pragma("unroll")                                                        \
    for (int nf = 0; nf < 2; ++nf)                                           \
      b[nf] = *(const s16x8*)(&Bs[CUR][wn * 32 + nf * 16 + l15][k0]);        \
    _Pragma("unroll")                                                        \
    for (int mf = 0; mf < 2; ++mf)                                           \
      _Pragma("unroll")                                                      \
      for (int nf = 0; nf < 2; ++nf)                                         \
        acc[mf][nf] = __builtin_amdgcn_mfma_f32_16x16x32_bf16(               \
            a[mf], b[nf], acc[mf][nf], 0, 0, 0);                             \
  }

  G1_ISSUE(0);
#pragma unroll 2
  for (int t = 0; t < DIM / BK; ++t) {
    const int cur = t & 1;
    G1_WRITE(cur);                       // waits on this step's loads
    if (t < DIM / BK - 1) G1_ISSUE((t + 1) * BK);  // next tile in flight
    __syncthreads();                     // single barrier per step (dbuf)
    G1_COMPUTE(cur);
  }

  // ---- in-block row normalization across the 8 waves' 32-col slices ----
#pragma unroll
  for (int mf = 0; mf < 2; ++mf)
#pragma unroll
    for (int r = 0; r < 4; ++r) {
      float s = acc[mf][0][r] * acc[mf][0][r] + acc[mf][1][r] * acc[mf][1][r];
#pragma unroll
      for (int o = 1; o < 16; o <<= 1) s += __shfl_xor(s, o, 16);
      if (l15 == 0) rowsq[wn][mf * 16 + lhi * 4 + r] = s;
    }
  __syncthreads();
#pragma unroll
  for (int mf = 0; mf < 2; ++mf)
#pragma unroll
    for (int r = 0; r < 4; ++r) {
      int lrow = mf * 16 + lhi * 4 + r;
      float n2 = 0.0f;
#pragma unroll
      for (int w = 0; w < 8; ++w) n2 += rowsq[w][lrow];
      float inv = 1.0f / fmaxf(sqrtf(n2), 1e-12f);  // F.normalize eps
#pragma unroll
      for (int nf = 0; nf < 2; ++nf) {
        int col = wn * 32 + nf * 16 + l15;
        Zb[(size_t)(rb + lrow) * DP + col] = f2bf(acc[mf][nf][r] * inv);
      }
    }
#undef G1_ISSUE
#undef G1_WRITE
#undef G1_COMPUTE
}

// GEMM2: out = -sqrt(max(1 + pp[k] - 2 * (Zb @ Pb^T), 0)); Zb normalized.
// BM=128, BN=128, BK=32 -> 8 K-steps, LDS 40 KB -> 3 blocks/CU.
// 2-phase reg-staged dbuf; XCD-aware swizzle (16x16 tile region per XCD).
__global__ __launch_bounds__(256, 3)
void k_gemm2(const unsigned short* __restrict__ Zb,
             const unsigned short* __restrict__ Pb,
             const float* __restrict__ pp, float* __restrict__ out) {
  constexpr int BM = 128, BN = 128, BK = 32, LD = BK + 8;
  __shared__ __align__(16) unsigned short As[2][BM][LD];  // 20480 B
  __shared__ __align__(16) unsigned short Bs[2][BN][LD];  // 20480 B

  const int tid  = threadIdx.x;
  const int lane = tid & 63;
  const int wv   = tid >> 6;
  const int wm   = wv >> 1;
  const int wn   = wv & 1;
  const int l15  = lane & 15;
  const int lhi  = lane >> 4;

  // XCD swizzle: 2048 blocks; xcd = bid%8 gets a contiguous 16(row)x16(col)
  // tile region -> per-XCD working set = 1MB Zb + 1MB Pb (L2-resident).
  const int bid = blockIdx.x;
  const int xcd = bid & 7;
  const int loc = bid >> 3;                 // [0,256)
  const int bx  = xcd * 16 + (loc & 15);    // row tile [0,128)
  const int by  = loc >> 4;                 // col tile [0,16)
  const int rb  = bx * BM;
  const int cb  = by * BN;

  // staging: 128 rows x 32 bf16 per matrix per step = 2 s16x8 per thread
  const int srow = tid >> 2;                // [0,64), second chunk +64
  const int sch8 = (tid & 3) * 8;
  const unsigned short* abase = Zb + (size_t)(rb + srow) * DP + sch8;
  const unsigned short* bbase = Pb + (size_t)(cb + srow) * DP + sch8;

  f32x4 acc[4][4];
#pragma unroll
  for (int mf = 0; mf < 4; ++mf)
#pragma unroll
    for (int nf = 0; nf < 4; ++nf) acc[mf][nf] = (f32x4)0.0f;

  s16x8 ar[2], br[2];

#define G2_ISSUE(KB)                                                         \
  {                                                                          \
    _Pragma("unroll")                                                        \
    for (int i = 0; i < 2; ++i) {                                            \
      ar[i] = *(const s16x8*)(abase + (size_t)i * 64 * DP + (KB));           \
      br[i] = *(const s16x8*)(bbase + (size_t)i * 64 * DP + (KB));           \
    }                                                                        \
  }

#define G2_WRITE(CUR)                                                        \
  {                                                                          \
    _Pragma("unroll")                                                        \
    for (int i = 0; i < 2; ++i) {                                            \
      *(s16x8*)(&As[CUR][srow + i * 64][sch8]) = ar[i];                      \
      *(s16x8*)(&Bs[CUR][srow + i * 64][sch8]) = br[i];                      \
    }                                                                        \
  }

#define G2_COMPUTE(CUR)                                                      \
  {                                                                          \
    int k0 = lhi * 8;                                                        \
    s16x8 a[4], b[4];                                                        \
    _Pragma("unroll")                                                        \
    for (int mf = 0; mf < 4; ++mf)                                           \
      a[mf] = *(const s16x8*)(&As[CUR][wm * 64 + mf * 16 + l15][k0]);        \
    _Pragma("unroll")                                                        \
    for (int nf = 0; nf < 4; ++nf)                                           \
      b[nf] = *(const s16x8*)(&Bs[CUR][wn * 64 + nf * 16 + l15][k0]);        \
    _Pragma("unroll")                                                        \
    for (int mf = 0; mf < 4; ++mf)                                           \
      _Pragma("unroll")                                                      \
      for (int nf = 0; nf < 4; ++nf)                                         \
        acc[mf][nf] = __builtin_amdgcn_mfma_f32_16x16x32_bf16(               \
            a[mf], b[nf], acc[mf][nf], 0, 0, 0);                             \
  }

  G2_ISSUE(0);
#pragma unroll 2
  for (int t = 0; t < DP / BK; ++t) {
    const int cur = t & 1;
    G2_WRITE(cur);
    if (t < DP / BK - 1) G2_ISSUE((t + 1) * BK);
    __syncthreads();
    G2_COMPUTE(cur);
  }

  float ppv[4];
#pragma unroll
  for (int nf = 0; nf < 4; ++nf)
    ppv[nf] = pp[cb + wn * 64 + nf * 16 + l15];

#pragma unroll
  for (int mf = 0; mf < 4; ++mf)
#pragma unroll
    for (int r = 0; r < 4; ++r) {
      int row = rb + wm * 64 + mf * 16 + lhi * 4 + r;
#pragma unroll
      for (int nf = 0; nf < 4; ++nf) {
        int col  = cb + wn * 64 + nf * 16 + l15;
        float d2 = fmaxf(1.0f + ppv[nf] - 2.0f * acc[mf][nf][r], 0.0f);
        out[(size_t)row * NPROTO + col] = -sqrtf(d2);
      }
    }
#undef G2_ISSUE
#undef G2_WRITE
#undef G2_COMPUTE
}

extern "C" void kernel_launch(void* const* d_in, const int* in_sizes, int n_in,
                              void* d_out, int out_size, void* d_ws, size_t ws_size,
                              hipStream_t stream) {
  const float* X     = (const float*)d_in[0];  // [16384,1024]
  const float* mean  = (const float*)d_in[1];  // [1024]
  const float* proj  = (const float*)d_in[2];  // [1024,256]
  const float* proto = (const float*)d_in[3];  // [2048,256]
  float* out = (float*)d_out;                  // [16384,2048]

  char* ws = (char*)d_ws;
  // workspace layout (~9.5 MB total)
  size_t off = 0;
  unsigned short* Zb    = (unsigned short*)(ws + off); off += (size_t)N_ROWS * DP * 2;   // 8 MB
  unsigned short* projT = (unsigned short*)(ws + off); off += (size_t)DIM * DP * 2;      // 512 KB
  unsigned short* Pb    = (unsigned short*)(ws + off); off += (size_t)NPROTO * DP * 2;   // 1 MB
  float* pp             = (float*)(ws + off);          off += (size_t)NPROTO * 4;        // 8 KB

  hipLaunchKernelGGL(k_prep, dim3((DIM * DP) / 256 + NPROTO), dim3(256), 0,
                     stream, proj, proto, projT, Pb, pp);
  hipLaunchKernelGGL(k_gemm1, dim3(N_ROWS / 32), dim3(512), 0, stream,
                     X, mean, projT, Zb);
  hipLaunchKernelGGL(k_gemm2, dim3((N_ROWS / 128) * (NPROTO / 128)), dim3(256),
                     0, stream, Zb, Pb, pp, out);
}

// Round 5
// 67.321 us; speedup vs baseline: 1.7783x; 1.1760x over previous
//
#include <hip/hip_runtime.h>

// Problem shape (fixed by setup_inputs): B=8, Q=2048 -> N=16384 rows,
// D=1024, Dp=256, K=2048 prototypes.
#define N_ROWS 16384
#define DIM    1024
#define DP     256
#define NPROTO 2048

typedef float f32x4 __attribute__((ext_vector_type(4)));
typedef short s16x8 __attribute__((ext_vector_type(8)));
typedef short s16x4 __attribute__((ext_vector_type(4)));

__device__ __forceinline__ unsigned short f2bf(float f) {
  // round-to-nearest-even f32 -> bf16 (finite inputs only)
  unsigned int u = __builtin_bit_cast(unsigned int, f);
  u += 0x7FFFu + ((u >> 16) & 1u);
  return (unsigned short)(u >> 16);
}

// ---- fused prep: projT[j][d]=bf16(proj[d][j]); Pb=bf16(P); pp=rowsum(P^2) ----
__global__ void k_prep(const float* __restrict__ proj,
                       const float* __restrict__ P,
                       unsigned short* __restrict__ projT,
                       unsigned short* __restrict__ Pb,
                       float* __restrict__ pp) {
  int b = blockIdx.x;
  if (b < (DIM * DP) / 256) {
    int t = b * 256 + threadIdx.x;          // t = j*1024 + d, coalesced writes
    int j = t >> 10;
    int d = t & 1023;
    projT[t] = f2bf(proj[(size_t)d * DP + j]);
  } else {
    int k = b - (DIM * DP) / 256;
    int d = threadIdx.x;                    // 256 threads = Dp
    float v = P[(size_t)k * DP + d];
    Pb[(size_t)k * DP + d] = f2bf(v);
    float s = v * v;
#pragma unroll
    for (int o = 1; o < 64; o <<= 1) s += __shfl_xor(s, o, 64);
    __shared__ float ws4[4];
    if ((threadIdx.x & 63) == 0) ws4[threadIdx.x >> 6] = s;
    __syncthreads();
    if (threadIdx.x == 0) pp[k] = ws4[0] + ws4[1] + ws4[2] + ws4[3];
  }
}

// ---- FUSED: per block (64 rows):
//   phase 1: Z[64][256] = normalize_rows((X - mean) @ proj)  -> LDS (bf16)
//   phase 2: out[64][2048] = -sqrt(max(1 + pp - 2 * Z @ Pb^T, 0))
// 512 threads = 8 waves. Grid 256 blocks = 1/CU. No inter-block deps.
// LDS plan (bytes):
//   [0      , 33792 )  Zs   [64][264] bf16     (+8 pad -> ~2-way conflicts)
//   [33792  , 34048 )  invs [64]      f32
//   [34048  , 36096 )  rowsq[8][64]   f32
//   [36096  , 118016)  staging union:
//        phase1: As[2][64][40] (10240) + Bs[2][256][40] (40960)
//        phase2: Ps[2][512][40] (81920)
__global__ __launch_bounds__(512, 2)
void k_fused(const float* __restrict__ X, const float* __restrict__ mean,
             const unsigned short* __restrict__ projT,
             const unsigned short* __restrict__ Pb,
             const float* __restrict__ pp, float* __restrict__ out) {
  __shared__ __align__(16) unsigned char smem[118016];
  auto Zs    = (unsigned short(*)[264])(smem);                    // [64][264]
  auto invs  = (float*)(smem + 33792);                            // [64]
  auto rowsq = (float(*)[64])(smem + 34048);                      // [8][64]
  auto As    = (unsigned short(*)[64][40])(smem + 36096);         // [2][64][40]
  auto Bs    = (unsigned short(*)[256][40])(smem + 46336);        // [2][256][40]
  auto Ps    = (unsigned short(*)[512][40])(smem + 36096);        // [2][512][40]

  const int tid  = threadIdx.x;
  const int lane = tid & 63;
  const int wv   = tid >> 6;        // wave id 0..7
  const int l15  = lane & 15;
  const int lhi  = lane >> 4;
  const int rb   = blockIdx.x * 64;

  // phase-1 staging coords (per thread):
  //  A: 64 rows x 32 f32 = 512 f32x4 chunks -> 1/thread
  //  B: 256 rows x 32 bf16 = 1024 s16x8 chunks -> 2/thread
  const int arow = tid >> 3;
  const int ach4 = (tid & 7) * 4;
  const int brow = tid >> 2;             // [0,128), second chunk +128
  const int bch8 = (tid & 3) * 8;
  const float* xbase = X + (size_t)(rb + arow) * DIM + ach4;
  const float* mbase = mean + ach4;
  const unsigned short* pjbase = projT + (size_t)brow * DIM + bch8;

  // phase-2 staging coords: 512 rows x 32 bf16 = 2048 s16x8 -> 4/thread
  const int srow = tid >> 2;             // [0,128), chunks at +0/128/256/384
  const int sch8 = (tid & 3) * 8;

  // ================= phase 1 =================
  f32x4 acc[4][2];
#pragma unroll
  for (int mf = 0; mf < 4; ++mf)
#pragma unroll
    for (int nf = 0; nf < 2; ++nf) acc[mf][nf] = (f32x4)0.0f;

  f32x4 xr, mr;
  s16x8 b0r, b1r;

#define P1_ISSUE(KB)                                                         \
  {                                                                          \
    xr  = *(const f32x4*)(xbase + (KB));                                     \
    mr  = *(const f32x4*)(mbase + (KB));                                     \
    b0r = *(const s16x8*)(pjbase + (KB));                                    \
    b1r = *(const s16x8*)(pjbase + (size_t)128 * DIM + (KB));                \
  }

#define P1_WRITE(CUR)                                                        \
  {                                                                          \
    f32x4 c = xr - mr;                                                       \
    s16x4 v;                                                                 \
    v[0] = (short)f2bf(c[0]); v[1] = (short)f2bf(c[1]);                      \
    v[2] = (short)f2bf(c[2]); v[3] = (short)f2bf(c[3]);                      \
    *(s16x4*)(&As[CUR][arow][ach4])       = v;                               \
    *(s16x8*)(&Bs[CUR][brow][bch8])       = b0r;                             \
    *(s16x8*)(&Bs[CUR][brow + 128][bch8]) = b1r;                             \
  }

#define P1_COMPUTE(CUR)                                                      \
  {                                                                          \
    int k0 = lhi * 8;                                                        \
    s16x8 a[4], b[2];                                                        \
    _Pragma("unroll")                                                        \
    for (int mf = 0; mf < 4; ++mf)                                           \
      a[mf] = *(const s16x8*)(&As[CUR][mf * 16 + l15][k0]);                  \
    _Pragma("unroll")                                                        \
    for (int nf = 0; nf < 2; ++nf)                                           \
      b[nf] = *(const s16x8*)(&Bs[CUR][wv * 32 + nf * 16 + l15][k0]);        \
    _Pragma("unroll")                                                        \
    for (int mf = 0; mf < 4; ++mf)                                           \
      _Pragma("unroll")                                                      \
      for (int nf = 0; nf < 2; ++nf)                                         \
        acc[mf][nf] = __builtin_amdgcn_mfma_f32_16x16x32_bf16(               \
            a[mf], b[nf], acc[mf][nf], 0, 0, 0);                             \
  }

  P1_ISSUE(0);
#pragma unroll 2
  for (int t = 0; t < DIM / 32; ++t) {
    const int cur = t & 1;
    P1_WRITE(cur);
    if (t < DIM / 32 - 1) P1_ISSUE((t + 1) * 32);
    __syncthreads();
    P1_COMPUTE(cur);
  }
#undef P1_ISSUE
#undef P1_WRITE
#undef P1_COMPUTE

  // issue phase-2 step-0 global loads NOW (latency hides under the epilogue)
  s16x8 pr[4];
#pragma unroll
  for (int i = 0; i < 4; ++i)
    pr[i] = *(const s16x8*)(Pb + (size_t)(srow + i * 128) * DP + sch8);

  // ---- phase-1 epilogue: row norms + normalized Z -> LDS ----
#pragma unroll
  for (int mf = 0; mf < 4; ++mf)
#pragma unroll
    for (int r = 0; r < 4; ++r) {
      float s = acc[mf][0][r] * acc[mf][0][r] + acc[mf][1][r] * acc[mf][1][r];
#pragma unroll
      for (int o = 1; o < 16; o <<= 1) s += __shfl_xor(s, o, 16);
      if (l15 == 0) rowsq[wv][mf * 16 + lhi * 4 + r] = s;
    }
  __syncthreads();      // also: all phase-1 LDS reads complete after this
  if (tid < 64) {
    float n2 = 0.0f;
#pragma unroll
    for (int w = 0; w < 8; ++w) n2 += rowsq[w][tid];
    invs[tid] = 1.0f / fmaxf(sqrtf(n2), 1e-12f);  // F.normalize eps
  }
  __syncthreads();
#pragma unroll
  for (int mf = 0; mf < 4; ++mf)
#pragma unroll
    for (int r = 0; r < 4; ++r) {
      int row   = mf * 16 + lhi * 4 + r;
      float inv = invs[row];
#pragma unroll
      for (int nf = 0; nf < 2; ++nf)
        Zs[row][wv * 32 + nf * 16 + l15] = f2bf(acc[mf][nf][r] * inv);
    }
  // (Zs-write -> phase-2-compute ordering is covered by the step-0 barrier)

  // ================= phase 2 =================
  // 4 column-tiles of 512 protos; per tile: K = 256 in 8 steps of 32.
  // Each wave owns a 64x64 out slice per tile (acc2[4][4], 16 MFMA/step).
#pragma unroll
  for (int ct = 0; ct < 4; ++ct) {
    f32x4 acc2[4][4];
#pragma unroll
    for (int mf = 0; mf < 4; ++mf)
#pragma unroll
      for (int nf = 0; nf < 4; ++nf) acc2[mf][nf] = (f32x4)0.0f;

#pragma unroll
    for (int ks = 0; ks < 8; ++ks) {
      const int s   = ct * 8 + ks;
      const int cur = s & 1;
      // write previously-issued regs into LDS
#pragma unroll
      for (int i = 0; i < 4; ++i)
        *(s16x8*)(&Ps[cur][srow + i * 128][sch8]) = pr[i];
      // issue next step's loads
      if (s < 31) {
        const int nct = (s + 1) >> 3;
        const int nks = (s + 1) & 7;
#pragma unroll
        for (int i = 0; i < 4; ++i)
          pr[i] = *(const s16x8*)(Pb +
              (size_t)(nct * 512 + srow + i * 128) * DP + nks * 32 + sch8);
      }
      __syncthreads();
      // compute: A from Zs (resident), B from Ps[cur]
      {
        s16x8 a[4], b[4];
        const int kz = ks * 32 + lhi * 8;
        const int k0 = lhi * 8;
#pragma unroll
        for (int mf = 0; mf < 4; ++mf)
          a[mf] = *(const s16x8*)(&Zs[mf * 16 + l15][kz]);
#pragma unroll
        for (int nf = 0; nf < 4; ++nf)
          b[nf] = *(const s16x8*)(&Ps[cur][wv * 64 + nf * 16 + l15][k0]);
#pragma unroll
        for (int mf = 0; mf < 4; ++mf)
#pragma unroll
          for (int nf = 0; nf < 4; ++nf)
            acc2[mf][nf] = __builtin_amdgcn_mfma_f32_16x16x32_bf16(
                a[mf], b[nf], acc2[mf][nf], 0, 0, 0);
      }
    }

    // ---- epilogue for this column tile ----
    float ppv[4];
#pragma unroll
    for (int nf = 0; nf < 4; ++nf)
      ppv[nf] = pp[ct * 512 + wv * 64 + nf * 16 + l15];
#pragma unroll
    for (int mf = 0; mf < 4; ++mf)
#pragma unroll
      for (int r = 0; r < 4; ++r) {
        int row = rb + mf * 16 + lhi * 4 + r;
#pragma unroll
        for (int nf = 0; nf < 4; ++nf) {
          int col  = ct * 512 + wv * 64 + nf * 16 + l15;
          float d2 = fmaxf(1.0f + ppv[nf] - 2.0f * acc2[mf][nf][r], 0.0f);
          out[(size_t)row * NPROTO + col] = -sqrtf(d2);
        }
      }
  }
}

extern "C" void kernel_launch(void* const* d_in, const int* in_sizes, int n_in,
                              void* d_out, int out_size, void* d_ws, size_t ws_size,
                              hipStream_t stream) {
  const float* X     = (const float*)d_in[0];  // [16384,1024]
  const float* mean  = (const float*)d_in[1];  // [1024]
  const float* proj  = (const float*)d_in[2];  // [1024,256]
  const float* proto = (const float*)d_in[3];  // [2048,256]
  float* out = (float*)d_out;                  // [16384,2048]

  char* ws = (char*)d_ws;
  // workspace layout (~1.5 MB total)
  size_t off = 0;
  unsigned short* projT = (unsigned short*)(ws + off); off += (size_t)DIM * DP * 2;    // 512 KB
  unsigned short* Pb    = (unsigned short*)(ws + off); off += (size_t)NPROTO * DP * 2; // 1 MB
  float* pp             = (float*)(ws + off);          off += (size_t)NPROTO * 4;      // 8 KB

  hipLaunchKernelGGL(k_prep, dim3((DIM * DP) / 256 + NPROTO), dim3(256), 0,
                     stream, proj, proto, projT, Pb, pp);
  hipLaunchKernelGGL(k_fused, dim3(N_ROWS / 64), dim3(512), 0, stream,
                     X, mean, projT, Pb, pp, out);
}